// Round 9
// baseline (45.595 us; speedup 1.0000x reference)
//
#include <hip/hip_runtime.h>
#include <hip/hip_bf16.h>

// Hopf oscillator scan: B=32, T=1000, D=512.
// Producer/consumer wave specialization, 256 blocks x 128 threads (2 waves):
//   wave 0 (consumer): pure LDS+VALU recurrence (reg-burst reads, inline
//     writes, phi in revolutions for raw v_sin/v_cos).
//   wave 1 (producer): global_load_lds dwordx4 into 5-deep IN ring (issue 4
//     bodies ahead, ~40KB in flight), drains OUT via b128 reads + nt stores.
// Raw s_barrier per body; producer hand-counted vmcnt(N), FIFO-simulated:
//   after(n) = 10*[(n+2<NB)+(n+3<NB)+(n+4<NB)] + 10*[(n>=2)+(n>=3)+(n>=4)]
// max 60 (< vmcnt cap 63). Consumer seals OUT with lgkm-only waitcnt.

#define B 32
#define T 1000
#define D 512
#define DTc 0.001f
#define K_IN 0.005f               // INPUT_SCALER * DT
#define KREV 7.95774715e-4f       // INPUT_SCALER * DT / (2*pi)
#define U 20                      // steps per body
#define NB (T / U)                // 50 bodies
#define NOPS (U / 4)              // 5 glds/drain ops per array per body
#define RING 5                    // IN ring depth

typedef float v4f __attribute__((ext_vector_type(4)));
typedef const __attribute__((address_space(1))) float gfloat;
typedef __attribute__((address_space(3))) float lfloat;

#define SCHEDB() __builtin_amdgcn_sched_barrier(0)
#define BAR()    __builtin_amdgcn_s_barrier()
// s_waitcnt simm16 (gfx9): [3:0]=vmcnt lo, [15:14]=vmcnt hi, [6:4]=expcnt, [11:8]=lgkmcnt
#define W_LGKM0  0xC07F   // lgkmcnt(0) only
#define W_VM30   0x4F7E   // vmcnt(30) only
#define W_VM40   0x8F78   // vmcnt(40) only
#define W_VM50   0xCF72   // vmcnt(50) only
#define W_VM60   0xCF7C   // vmcnt(60) only

__global__ __launch_bounds__(128, 1) void hopf_scan(
    const float* __restrict__ Xr, const float* __restrict__ Xi,
    const float* __restrict__ om,
    float* __restrict__ zr, float* __restrict__ zi) {
    const int tid = threadIdx.x;
    const int bb = blockIdx.x;            // 0..255
    const int b = bb >> 3;
    const int dblk = (bb & 7) << 6;       // 64-d block
    const size_t blkoff = (size_t)b * (T * D) + dblk;

    __shared__ __align__(16) float INr[RING][U][64];   // 5-deep input ring
    __shared__ __align__(16) float INi[RING][U][64];
    __shared__ __align__(16) float OUTr[2][U][64];     // double-buffered out
    __shared__ __align__(16) float OUTi[2][U][64];

    if (tid < 64) {
        // ---------------- consumer wave: LDS + VALU only ----------------
        const int i = tid;
        // rev/step: f_Hz * dt = (om*10 + 0.1) * dt
        const float od = __builtin_fmaf(om[dblk + i], 10.0f, 0.1f) * DTc;
        float r = 1.0f, phi = 0.0f, c = 1.0f, s = 0.0f;  // phi in revolutions

        BAR();                            // body 0 staged by producer
        int ib = 0;
        for (int n = 0; n < NB; ++n) {
            const int ob = n & 1;

            float xr[U], xi[U];
#pragma unroll
            for (int t = 0; t < U; ++t) {   // reg-burst: latency pipelines
                xr[t] = INr[ib][t][i];
                xi[t] = INi[ib][t][i];
            }
            SCHEDB();

#pragma unroll
            for (int t = 0; t < U; ++t) {
                const float omr2 = __builtin_fmaf(-r, r, 1.0f);   // 1 - r^2
                r = __builtin_fmaf(omr2 * r, DTc, r);             // + cubic*dt
                r = __builtin_fmaf(K_IN * xr[t], c, r);           // + K*xr*cos
                phi = __builtin_fmaf(-(KREV * xi[t]), s, phi + od);
                s = __builtin_amdgcn_sinf(phi);   // v_sin: input in revs
                c = __builtin_amdgcn_cosf(phi);
                // inline writes: issue slots hide in the sin-chain shadow
                OUTr[ob][t][i] = r * c;
                OUTi[ob][t][i] = r * s;
            }
            __builtin_amdgcn_s_waitcnt(W_LGKM0);  // seal OUT (nearly free)
            SCHEDB();
            BAR();
            ib = (ib == RING - 1) ? 0 : ib + 1;
        }
    } else {
        // ---------------- producer wave: all global traffic ----------------
        const int i = tid - 64;           // lane within wave
        const int ts = i >> 4;            // sub-step 0..3 of a glds op
        const int dq = (i & 15) << 2;     // d quad
        const float* __restrict__ xr_blk = Xr + blkoff;
        const float* __restrict__ xi_blk = Xi + blkoff;
        float* __restrict__ zr_blk = zr + blkoff;
        float* __restrict__ zi_blk = zi + blkoff;

        auto issueglds = [&](int body, int buf) {
#pragma unroll
            for (int k = 0; k < NOPS; ++k) {
                const size_t off = (size_t)(body * U + 4 * k + ts) * D + dq;
                __builtin_amdgcn_global_load_lds((gfloat*)(xr_blk + off),
                                                 (lfloat*)&INr[buf][4 * k][0], 16, 0, 0);
                __builtin_amdgcn_global_load_lds((gfloat*)(xi_blk + off),
                                                 (lfloat*)&INi[buf][4 * k][0], 16, 0, 0);
            }
        };
        auto drainbody = [&](int body) {
            const int ob = body & 1;
#pragma unroll
            for (int k = 0; k < NOPS; ++k) {
                const size_t off = (size_t)(body * U + 4 * k + ts) * D + dq;
                const v4f vr = *reinterpret_cast<const v4f*>(&OUTr[ob][4 * k + ts][dq]);
                const v4f vi = *reinterpret_cast<const v4f*>(&OUTi[ob][4 * k + ts][dq]);
                __builtin_nontemporal_store(vr, reinterpret_cast<v4f*>(zr_blk + off));
                __builtin_nontemporal_store(vi, reinterpret_cast<v4f*>(zi_blk + off));
            }
        };

        // prologue: bodies 0..3 in flight; body 0 landed when <=30 newer remain
        issueglds(0, 0);
        issueglds(1, 1);
        issueglds(2, 2);
        issueglds(3, 3);
        __builtin_amdgcn_s_waitcnt(W_VM30);
        SCHEDB();
        BAR();

        int bufn = 4;                     // buffer slot for body n+4
        for (int n = 0; n < NB; ++n) {
            if (n + 4 < NB) issueglds(n + 4, bufn);
            SCHEDB();
            if (n + 1 < NB) {
                // wait until body n+1's loads retired (FIFO-counted newer ops)
                const int after = 10 * ((n + 2 < NB) + (n + 3 < NB) + (n + 4 < NB))
                                + 10 * ((n >= 2) + (n >= 3) + (n >= 4));
                if (after >= 60)      __builtin_amdgcn_s_waitcnt(W_VM60);
                else if (after == 50) __builtin_amdgcn_s_waitcnt(W_VM50);
                else if (after == 40) __builtin_amdgcn_s_waitcnt(W_VM40);
                else                  __builtin_amdgcn_s_waitcnt(W_VM30);
            }
            SCHEDB();
            if (n >= 1) drainbody(n - 1);   // body n-1 sealed at barrier n-1
            SCHEDB();
            BAR();
            bufn = (bufn == RING - 1) ? 0 : bufn + 1;
        }
        drainbody(NB - 1);                  // sealed at final barrier
    }
}

extern "C" void kernel_launch(void* const* d_in, const int* in_sizes, int n_in,
                              void* d_out, int out_size, void* d_ws, size_t ws_size,
                              hipStream_t stream) {
    const float* Xr = (const float*)d_in[0];
    const float* Xi = (const float*)d_in[1];
    const float* om = (const float*)d_in[2];
    float* zr = (float*)d_out;
    float* zi = zr + (size_t)B * T * D;   // tuple output 2, flat-concatenated

    hopf_scan<<<dim3(B * D / 64), dim3(128), 0, stream>>>(Xr, Xi, om, zr, zi);
}